// Round 1
// baseline (108.208 us; speedup 1.0000x reference)
//
#include <hip/hip_runtime.h>
#include <stdint.h>

// Problem constants (from reference)
#define S 7
#define BB 2
#define CLS 20
#define NCELLS (8192 * S * S)        // 401408 cells total
#define CPB 64                       // cells per chunk == threads per block (1 wave)
#define THREADS 64
#define PRED_F 30                    // BB*5 + CLS
#define TGT_F 25                     // CLS + 5
#define NCHUNK 4                     // chunks per block (double-buffered pipeline)
#define NBLK_P (NCELLS / (CPB * NCHUNK))   // 1568 blocks

// Async 16B-per-lane global->LDS copy. LDS dest = wave-uniform base + lane*16
// (HW scatters lane*16; pass the UNIFORM base). Global src is per-lane.
#define ASYNC_CP16(gsrc, ldst)                                                  \
    __builtin_amdgcn_global_load_lds(                                           \
        (const __attribute__((address_space(1))) void*)(gsrc),                  \
        (__attribute__((address_space(3))) void*)(ldst), 16, 0, 0)

__device__ __forceinline__ float iou_fn(float ax, float ay, float aw, float ah,
                                        float bx, float by, float bw, float bh) {
    float ax1 = ax - aw * 0.5f, ay1 = ay - ah * 0.5f;
    float ax2 = ax + aw * 0.5f, ay2 = ay + ah * 0.5f;
    float bx1 = bx - bw * 0.5f, by1 = by - bh * 0.5f;
    float bx2 = bx + bw * 0.5f, by2 = by + bh * 0.5f;
    float iw = fmaxf(fminf(ax2, bx2) - fmaxf(ax1, bx1), 0.0f);
    float ih = fmaxf(fminf(ay2, by2) - fmaxf(ay1, by1), 0.0f);
    float inter = iw * ih;
    float uni = fabsf(aw * ah) + fabsf(bw * bh) - inter;
    return inter / (uni + 1e-6f);
}

// R6 structure: 4 chunks/block, double-buffered LDS, COUNTED vmcnt(15) so the
// next chunk's 15 global_load_lds stay in flight while computing the current
// chunk (T3/T4 pattern — never drain vmcnt to 0 mid-loop). Single wave per
// block -> no s_barrier anywhere in the main loop.
// NOTE (R5 pitfall, kept): do NOT fuse the final reduction via agent-scope flag
// atomics — L2 writeback/invalidate per op cost ~50 µs (measured 107->157 µs).
__global__ __launch_bounds__(THREADS) void yolo_main(const float* __restrict__ pred,
                                                     const float* __restrict__ tgt,
                                                     float4* __restrict__ part) {
    __shared__ float lp[2][CPB * PRED_F];   // 2 x 7680 B
    __shared__ float lt[2][CPB * TGT_F];    // 2 x 6400 B   (total 28.16 KB -> 5 blk/CU)

    const int b = blockIdx.x;
    const int t = threadIdx.x;              // == lane (single wave)

    // 15 global_load_lds per stage: pred = 7 full 1024B rounds + 512B tail,
    // tgt = 6 full rounds + 256B tail.
    auto stage = [&](int buf, int chunk) {
        const float* gp = pred + (size_t)chunk * (CPB * PRED_F) + t * 4;
        float* dp = &lp[buf][0];
        #pragma unroll
        for (int i = 0; i < 7; ++i) ASYNC_CP16(gp + i * 256, dp + i * 256);
        if (t < 32) ASYNC_CP16(gp + 7 * 256, dp + 7 * 256);
        const float* gt0 = tgt + (size_t)chunk * (CPB * TGT_F) + t * 4;
        float* dt = &lt[buf][0];
        #pragma unroll
        for (int i = 0; i < 6; ++i) ASYNC_CP16(gt0 + i * 256, dt + i * 256);
        if (t < 16) ASYNC_CP16(gt0 + 6 * 256, dt + 6 * 256);
    };

    float loss = 0.0f, iou_o = 0.0f, objs = 0.0f;

    stage(0, b);                             // prologue: chunk 0 -> buf 0

    #pragma unroll                           // full unroll -> static buf indices
    for (int i = 0; i < NCHUNK; ++i) {
        const int buf = i & 1;
        if (i + 1 < NCHUNK) {
            // WAR guard: ds_reads of the buffer we're about to overwrite
            // (computed at iter i-1) must have completed. Their results were
            // consumed, but the DMA write path doesn't order vs pending ds_read.
            asm volatile("s_waitcnt lgkmcnt(0)" ::: "memory");
            stage(buf ^ 1, b + (i + 1) * NBLK_P);      // prefetch next chunk
            asm volatile("s_waitcnt vmcnt(15)" ::: "memory");  // chunk i landed,
                                                               // chunk i+1 in flight
        } else {
            asm volatile("s_waitcnt vmcnt(0)" ::: "memory");   // last chunk: drain
        }

        const float* pp = &lp[buf][t * PRED_F];
        const float* tp = &lt[buf][t * TGT_F];

        float tconf = tp[CLS + 0];
        float tx = tp[CLS + 1], ty = tp[CLS + 2], tw = tp[CLS + 3], th = tp[CLS + 4];

        float iou0 = iou_fn(pp[CLS + 1], pp[CLS + 2], pp[CLS + 3], pp[CLS + 4],
                            tx, ty, tw, th);
        float iou1 = iou_fn(pp[CLS + 6], pp[CLS + 7], pp[CLS + 8], pp[CLS + 9],
                            tx, ty, tw, th);
        // jnp.argmax takes FIRST max on ties -> box 1 only on strict greater
        int sel = (iou1 > iou0) ? 1 : 0;
        float iou_best = fmaxf(iou0, iou1);

        const float* pb = pp + CLS + sel * 5;
        float dx = tx - pb[1], dy = ty - pb[2];
        float center = dx * dx + dy * dy;
        float dw = sqrtf(tw) - sqrtf(fabsf(pb[3]));
        float dh = sqrtf(th) - sqrtf(fabsf(pb[4]));
        float wh = dw * dw + dh * dh;
        float dc = tconf - pb[0];
        float conf_sq = dc * dc;

        float cls_sq = 0.0f;
        #pragma unroll
        for (int k = 0; k < CLS; ++k) {
            float d = pp[k] - tp[k];
            cls_sq += d * d;
        }

        float objf = (tconf == 1.0f) ? 1.0f : 0.0f;
        loss  += objf * (5.0f * (center + wh) + conf_sq + cls_sq)
               + (1.0f - objf) * 0.5f * conf_sq;
        iou_o += objf * iou_best;
        objs  += objf;
    }

    // One 64-lane shuffle reduction for all 4 chunks, one float4 store per block.
    #pragma unroll
    for (int off = 32; off > 0; off >>= 1) {
        loss  += __shfl_down(loss,  off, 64);
        iou_o += __shfl_down(iou_o, off, 64);
        objs  += __shfl_down(objs,  off, 64);
    }
    if (t == 0) {
        part[b] = make_float4(loss, iou_o, objs, 0.0f);
    }
}

__global__ __launch_bounds__(1024) void yolo_fin(const float4* __restrict__ part,
                                                 float* __restrict__ out) {
    __shared__ float red[3][1024 / 64];
    float l = 0.f, i = 0.f, o = 0.f;
    for (int k = threadIdx.x; k < NBLK_P; k += 1024) {   // 2 coalesced float4 iters
        float4 v = part[k];
        l += v.x;
        i += v.y;
        o += v.z;
    }
    #pragma unroll
    for (int off = 32; off > 0; off >>= 1) {
        l += __shfl_down(l, off, 64);
        i += __shfl_down(i, off, 64);
        o += __shfl_down(o, off, 64);
    }
    const int wave = threadIdx.x >> 6, lane = threadIdx.x & 63;
    if (lane == 0) {
        red[0][wave] = l;
        red[1][wave] = i;
        red[2][wave] = o;
    }
    __syncthreads();
    if (threadIdx.x == 0) {
        float L = 0.f, I = 0.f, O = 0.f;
        #pragma unroll
        for (int w = 0; w < 1024 / 64; ++w) {
            L += red[0][w];
            I += red[1][w];
            O += red[2][w];
        }
        out[0] = L;
        out[1] = I / fmaxf(O, 1.0f);
    }
}

extern "C" void kernel_launch(void* const* d_in, const int* in_sizes, int n_in,
                              void* d_out, int out_size, void* d_ws, size_t ws_size,
                              hipStream_t stream) {
    const float* pred = (const float*)d_in[0];
    const float* tgt  = (const float*)d_in[1];
    float* out = (float*)d_out;
    float4* part = (float4*)d_ws;   // NBLK_P float4 partials = 25 KB (fully overwritten)

    yolo_main<<<NBLK_P, THREADS, 0, stream>>>(pred, tgt, part);
    yolo_fin<<<1, 1024, 0, stream>>>(part, out);
}

// Round 2
// 106.029 us; speedup vs baseline: 1.0205x; 1.0205x over previous
//
#include <hip/hip_runtime.h>
#include <stdint.h>

// Problem constants (from reference)
#define S 7
#define BB 2
#define CLS 20
#define NCELLS (8192 * S * S)        // 401408
#define CPB 64                       // cells per block == threads per block (1 wave)
#define THREADS 64
#define NBLK (NCELLS / CPB)          // 6272
#define PRED_F 30                    // BB*5 + CLS
#define TGT_F 25                     // CLS + 5

// Async 16B-per-lane global->LDS copy. LDS dest = wave-uniform base + lane*16.
#define ASYNC_CP16(gsrc, ldst)                                                  \
    __builtin_amdgcn_global_load_lds(                                           \
        (const __attribute__((address_space(1))) void*)(gsrc),                  \
        (__attribute__((address_space(3))) void*)(ldst), 16, 0, 0)

__device__ __forceinline__ float iou_fn(float ax, float ay, float aw, float ah,
                                        float bx, float by, float bw, float bh) {
    float ax1 = ax - aw * 0.5f, ay1 = ay - ah * 0.5f;
    float ax2 = ax + aw * 0.5f, ay2 = ay + ah * 0.5f;
    float bx1 = bx - bw * 0.5f, by1 = by - bh * 0.5f;
    float bx2 = bx + bw * 0.5f, by2 = by + bh * 0.5f;
    float iw = fmaxf(fminf(ax2, bx2) - fmaxf(ax1, bx1), 0.0f);
    float ih = fmaxf(fminf(ay2, by2) - fmaxf(ay1, by1), 0.0f);
    float inter = iw * ih;
    float uni = fabsf(aw * ah) + fabsf(bw * bh) - inter;
    return inter / (uni + 1e-6f);
}

// R3 structure (best measured, reverted to after R6 regression): one wave per
// block, ~11 blocks/CU (14.08 KB LDS), async global->LDS staging, one float4
// partial per block. Block-level parallelism (11 x ~14 KB DMA in flight per
// CU) IS the pipeline — R6's explicit double-buffer (5 blocks/CU, counted
// vmcnt) measured +2.8 us.
// NOTE (R5 pitfall): do NOT fuse the final reduction via agent-scope flag
// atomics — on CDNA4 agent-scope release/acquire compile to L2 writeback/
// invalidate per op; the spin loop's repeated invalidates cost ~50 µs and
// wreck input locality for co-resident blocks (measured R5: 107->157 µs).
__global__ __launch_bounds__(THREADS) void yolo_main(const float* __restrict__ pred,
                                                     const float* __restrict__ tgt,
                                                     float4* __restrict__ part) {
    __shared__ float lp[CPB * PRED_F];   // 7680 B = 1920 floats
    __shared__ float lt[CPB * TGT_F];    // 6400 B = 1600 floats

    const int b = blockIdx.x;
    const int t = threadIdx.x;           // == lane (single wave)

    // pred chunk: 7680 B = 7 full 1024B wave-rounds + 512B tail (lanes 0..31)
    const float* gp = pred + (size_t)b * (CPB * PRED_F) + t * 4;  // per-lane 16B slot
    #pragma unroll
    for (int i = 0; i < 7; ++i) {
        ASYNC_CP16(gp + i * 256, lp + i * 256);
    }
    if (t < 32) {
        ASYNC_CP16(gp + 7 * 256, lp + 7 * 256);
    }
    // tgt chunk: 6400 B = 6 full 1024B wave-rounds + 256B tail (lanes 0..15)
    const float* gt = tgt + (size_t)b * (CPB * TGT_F) + t * 4;
    #pragma unroll
    for (int i = 0; i < 6; ++i) {
        ASYNC_CP16(gt + i * 256, lt + i * 256);
    }
    if (t < 16) {
        ASYNC_CP16(gt + 6 * 256, lt + 6 * 256);
    }
    __syncthreads();   // drains vmcnt (global_load_lds) before LDS reads

    const float* pp = lp + t * PRED_F;
    const float* tp = lt + t * TGT_F;

    float tconf = tp[CLS + 0];
    float tx = tp[CLS + 1], ty = tp[CLS + 2], tw = tp[CLS + 3], th = tp[CLS + 4];

    float iou0 = iou_fn(pp[CLS + 1], pp[CLS + 2], pp[CLS + 3], pp[CLS + 4], tx, ty, tw, th);
    float iou1 = iou_fn(pp[CLS + 6], pp[CLS + 7], pp[CLS + 8], pp[CLS + 9], tx, ty, tw, th);
    // jnp.argmax takes FIRST max on ties -> box 1 only on strict greater
    int sel = (iou1 > iou0) ? 1 : 0;
    float iou_best = fmaxf(iou0, iou1);

    const float* pb = pp + CLS + sel * 5;
    float dx = tx - pb[1], dy = ty - pb[2];
    float center = dx * dx + dy * dy;
    float dw = sqrtf(tw) - sqrtf(fabsf(pb[3]));
    float dh = sqrtf(th) - sqrtf(fabsf(pb[4]));
    float wh = dw * dw + dh * dh;
    float dc = tconf - pb[0];
    float conf_sq = dc * dc;

    float cls_sq = 0.0f;
    #pragma unroll
    for (int k = 0; k < CLS; ++k) {
        float d = pp[k] - tp[k];
        cls_sq += d * d;
    }

    float objf = (tconf == 1.0f) ? 1.0f : 0.0f;
    float loss = objf * (5.0f * (center + wh) + conf_sq + cls_sq)
               + (1.0f - objf) * 0.5f * conf_sq;
    float iou_o = objf * iou_best;

    // 64-lane shuffle reduction, then ONE float4 partial store per block.
    #pragma unroll
    for (int off = 32; off > 0; off >>= 1) {
        loss  += __shfl_down(loss,  off, 64);
        iou_o += __shfl_down(iou_o, off, 64);
        objf  += __shfl_down(objf,  off, 64);
    }
    if (t == 0) {
        part[b] = make_float4(loss, iou_o, objf, 0.0f);
    }
}

__global__ __launch_bounds__(1024) void yolo_fin(const float4* __restrict__ part,
                                                 float* __restrict__ out) {
    __shared__ float red[3][1024 / 64];
    float l = 0.f, i = 0.f, o = 0.f;
    for (int k = threadIdx.x; k < NBLK; k += 1024) {   // ~6 coalesced float4 iters
        float4 v = part[k];
        l += v.x;
        i += v.y;
        o += v.z;
    }
    #pragma unroll
    for (int off = 32; off > 0; off >>= 1) {
        l += __shfl_down(l, off, 64);
        i += __shfl_down(i, off, 64);
        o += __shfl_down(o, off, 64);
    }
    const int wave = threadIdx.x >> 6, lane = threadIdx.x & 63;
    if (lane == 0) {
        red[0][wave] = l;
        red[1][wave] = i;
        red[2][wave] = o;
    }
    __syncthreads();
    if (threadIdx.x == 0) {
        float L = 0.f, I = 0.f, O = 0.f;
        #pragma unroll
        for (int w = 0; w < 1024 / 64; ++w) {
            L += red[0][w];
            I += red[1][w];
            O += red[2][w];
        }
        out[0] = L;
        out[1] = I / fmaxf(O, 1.0f);
    }
}

extern "C" void kernel_launch(void* const* d_in, const int* in_sizes, int n_in,
                              void* d_out, int out_size, void* d_ws, size_t ws_size,
                              hipStream_t stream) {
    const float* pred = (const float*)d_in[0];
    const float* tgt  = (const float*)d_in[1];
    float* out = (float*)d_out;
    float4* part = (float4*)d_ws;   // NBLK float4 partials = 100 KB (fully overwritten)

    yolo_main<<<NBLK, THREADS, 0, stream>>>(pred, tgt, part);
    yolo_fin<<<1, 1024, 0, stream>>>(part, out);
}